// Round 9
// baseline (153.450 us; speedup 1.0000x reference)
//
#include <hip/hip_runtime.h>
#include <math.h>

typedef unsigned short u16;
typedef unsigned int u32;
typedef unsigned long long u64;
typedef __attribute__((ext_vector_type(8))) short short8;
typedef __attribute__((ext_vector_type(4))) float f32x4;

#define CDIM 512
#define NTOK 4096
#define MTOK 1024
#define NHEAD 8

// ---------- bf16 helpers ----------
__device__ __forceinline__ u16 f2bf(float x) {
  u32 b = __float_as_uint(x);
  u32 r = (b + 0x7FFFu + ((b >> 16) & 1u)) >> 16;
  return (u16)r;
}
__device__ __forceinline__ float bf2f(u16 u) {
  return __uint_as_float(((u32)u) << 16);
}

__device__ __forceinline__ void gload16(const void* g, void* l) {
  __builtin_amdgcn_global_load_lds(
      (const __attribute__((address_space(1))) u32*)g,
      (__attribute__((address_space(3))) u32*)l, 16, 0, 0);
}

// ==================== fragment-packing prep ====================
// Frag layout (1024 B each): packed[frag*512 + l*8 + j] =
//   Mat[mt*16 + (l&15)][kt*32 + (l>>4)*8 + j],  frag = mt*Kf + kt.
__global__ __launch_bounds__(256) void prep_pack(
    const float* __restrict__ Wq, const float* __restrict__ Wkv,
    const float* __restrict__ Wp, const float* __restrict__ Wsr,
    const float* __restrict__ x0, const float* __restrict__ x1,
    u16* __restrict__ WqTph, u16* __restrict__ WqTpl,
    u16* __restrict__ WkvTph, u16* __restrict__ WkvTpl,
    u16* __restrict__ WpTph, u16* __restrict__ WpTpl,
    u16* __restrict__ W2Tph, u16* __restrict__ W2Tpl,
    u16* __restrict__ xqh, u16* __restrict__ xql,
    u16* __restrict__ xch, u16* __restrict__ xcl) {
  const int b = blockIdx.x, t = threadIdx.x;
  const int fid = t >> 6, l = t & 63, lr = l & 15, lc = l >> 4;
  float v[8];
  u16* dh; u16* dl; size_t dst;
  if (b < 512) {
    const float* W; u16 *oh, *ol; int N, f;
    if (b < 128)      { W = Wq;  oh = WqTph;  ol = WqTpl;  N = 512;  f = b * 4 + fid; }
    else if (b < 384) { W = Wkv; oh = WkvTph; ol = WkvTpl; N = 1024; f = (b - 128) * 4 + fid; }
    else              { W = Wp;  oh = WpTph;  ol = WpTpl;  N = 512;  f = (b - 384) * 4 + fid; }
    const int nt = f >> 4, kt = f & 15;
    const int n = nt * 16 + lr, k0 = kt * 32 + lc * 8;
#pragma unroll
    for (int j = 0; j < 8; ++j) v[j] = W[(size_t)(k0 + j) * N + n];
    dh = oh; dl = ol; dst = (size_t)f * 512 + l * 8;
  } else if (b < 1024) {
    const int f = (b - 512) * 4 + fid;          // ot*64 + kt (2048 frags)
    const int ot = f >> 6, kt = f & 63;
    const int o = ot * 16 + lr;
    const int r0 = kt * 32 + lc * 8;
    const int p = r0 >> 9, i0 = r0 & 511;
#pragma unroll
    for (int j = 0; j < 8; ++j) v[j] = Wsr[(size_t)o * 2048 + (size_t)(i0 + j) * 4 + p];
    dh = W2Tph; dl = W2Tpl; dst = (size_t)f * 512 + l * 8;
  } else if (b < 3072) {
    const int g = (b - 1024) * 4 + fid;         // br(2) x mt(256) x kt(16)
    const int br = g >> 12, fl = g & 4095;
    const int mt = fl >> 4, kt = fl & 15;
    const float* x = br ? x1 : x0;
    const float* src = x + (size_t)(mt * 16 + lr) * 512 + kt * 32 + lc * 8;
#pragma unroll
    for (int j = 0; j < 8; ++j) v[j] = src[j];
    dh = xqh; dl = xql; dst = (size_t)br * 2097152 + (size_t)fl * 512 + l * 8;
  } else {
    const int g = (b - 3072) * 4 + fid;         // br(2) x mt(64) x kt(64)
    const int br = g >> 12, fl = g & 4095;
    const int mt = fl >> 6, kt = fl & 63;
    const int m = mt * 16 + lr;
    const int p = kt >> 4, i0 = (kt * 32 + lc * 8) & 511;
    const int token = (((m >> 5) * 2 + (p >> 1)) << 6) + ((m & 31) * 2 + (p & 1));
    const float* x = br ? x1 : x0;
    const float* src = x + (size_t)token * 512 + i0;
#pragma unroll
    for (int j = 0; j < 8; ++j) v[j] = src[j];
    dh = xch; dl = xcl; dst = (size_t)br * 2097152 + (size_t)fl * 512 + l * 8;
  }
  short8 hv, lv;
#pragma unroll
  for (int j = 0; j < 8; ++j) {
    u16 hi = f2bf(v[j]);
    hv[j] = (short)hi;
    lv[j] = (short)f2bf(v[j] - bf2f(hi));
  }
  *(short8*)&dh[dst] = hv;
  *(short8*)&dl[dst] = lv;
}

// ==================== split-bf16 MFMA GEMM (frag-packed, 3-buf counted-vmcnt pipeline) ====================
// A/B: frag-packed, Kf frags per row-frag. ktiles K-steps starting at kcid*ktiles.
// modes: 0 = f32 at Of + bz*M*N; 1 = f32 (+bias)*mask at Of + br*M*N;
//        2 = bf16(acc*oscale) row-major at Ob + br*M*N.
__global__ __launch_bounds__(256) void gemm_sp(
    const u16* __restrict__ A0h, const u16* __restrict__ A0l,
    const u16* __restrict__ A1h, const u16* __restrict__ A1l,
    const u16* __restrict__ BTh, const u16* __restrict__ BTl,
    int M, int N, int Kf, int ktiles, int nk, int mode,
    float* __restrict__ Of, u16* __restrict__ Ob,
    const float* __restrict__ bias,
    const float* __restrict__ mask0, const float* __restrict__ mask1,
    float oscale) {
  const int t = threadIdx.x;
  const int w = t >> 6;
  const int l = t & 63;
  const int lr = l & 15;
  const int lc = l >> 4;

  // bijective XCD-chunk swizzle (all grids have total % 8 == 0)
  const int nwx = gridDim.x, nwy = gridDim.y;
  const int total = nwx * nwy * gridDim.z;
  const int L = blockIdx.x + nwx * (blockIdx.y + nwy * blockIdx.z);
  const int chunk = total >> 3;
  int W = (L & 7) * chunk + (L >> 3);
  const int wx = W % nwx; W /= nwx;
  const int wy = W % nwy;
  const int bz = W / nwy;

  const int br = bz / nk, kcid = bz % nk;
  const int row0 = wy * 64;
  const int col0 = wx * 64;
  const u16* Ah = br ? A1h : A0h;
  const u16* Al = br ? A1l : A0l;

  const size_t abase = (size_t)((row0 >> 4) + w) * Kf * 512 + (size_t)l * 8;
  const size_t bbase = (size_t)((col0 >> 4) + w) * Kf * 512 + (size_t)l * 8;

  // 3-buffer rotation, 2 stages in flight
  __shared__ u16 sAh[3][2048], sAl[3][2048], sBh[3][2048], sBl[3][2048];

  auto stage = [&](int buf, int kt) {
    gload16(Ah + abase + (size_t)kt * 512, (void*)&sAh[buf][w * 512]);
    gload16(Al + abase + (size_t)kt * 512, (void*)&sAl[buf][w * 512]);
    gload16(BTh + bbase + (size_t)kt * 512, (void*)&sBh[buf][w * 512]);
    gload16(BTl + bbase + (size_t)kt * 512, (void*)&sBl[buf][w * 512]);
  };

  f32x4 acc[2][2];
#pragma unroll
  for (int a = 0; a < 2; ++a)
#pragma unroll
    for (int b2 = 0; b2 < 2; ++b2) acc[a][b2] = (f32x4){0.f, 0.f, 0.f, 0.f};

  const int kt0 = kcid * ktiles;
  const int wr = (w >> 1) * 2;
  const int wc = (w & 1) * 2;

  // prologue: two tiles in flight
  stage(0, kt0);
  stage(1, kt0 + 1);

  int cur = 0;
  for (int ti = 0; ti < ktiles; ++ti) {
    // wait only MY oldest 4 loads (buf cur); the newer 4 stay in flight
    if (ti + 1 < ktiles) {
      asm volatile("s_waitcnt vmcnt(4)" ::: "memory");
    } else {
      asm volatile("s_waitcnt vmcnt(0)" ::: "memory");
    }
    __builtin_amdgcn_s_barrier();        // all waves' buf(cur) staged
    __builtin_amdgcn_sched_barrier(0);

    // issue prefetch 2 tiles ahead into the free buffer
    if (ti + 2 < ktiles) {
      int nb = cur + 2; if (nb >= 3) nb -= 3;
      stage(nb, kt0 + ti + 2);
    }

    short8 ah[2], al[2], bh[2], bl[2];
#pragma unroll
    for (int i = 0; i < 2; ++i) {
      ah[i] = *(const short8*)&sAh[cur][(wr + i) * 512 + l * 8];
      al[i] = *(const short8*)&sAl[cur][(wr + i) * 512 + l * 8];
      bh[i] = *(const short8*)&sBh[cur][(wc + i) * 512 + l * 8];
      bl[i] = *(const short8*)&sBl[cur][(wc + i) * 512 + l * 8];
    }
#pragma unroll
    for (int mt = 0; mt < 2; ++mt)
#pragma unroll
      for (int nt2 = 0; nt2 < 2; ++nt2) {
        acc[mt][nt2] = __builtin_amdgcn_mfma_f32_16x16x32_bf16(ah[mt], bh[nt2], acc[mt][nt2], 0, 0, 0);
        acc[mt][nt2] = __builtin_amdgcn_mfma_f32_16x16x32_bf16(ah[mt], bl[nt2], acc[mt][nt2], 0, 0, 0);
        acc[mt][nt2] = __builtin_amdgcn_mfma_f32_16x16x32_bf16(al[mt], bh[nt2], acc[mt][nt2], 0, 0, 0);
      }
    cur += 1; if (cur >= 3) cur -= 3;
  }

  const int rowb = row0 + (w >> 1) * 32;
  const int colb = col0 + (w & 1) * 32;
  const size_t obase = (mode == 0) ? (size_t)bz * M * N : (size_t)br * M * N;
#pragma unroll
  for (int mt = 0; mt < 2; ++mt)
#pragma unroll
    for (int nt2 = 0; nt2 < 2; ++nt2) {
      const int col = colb + nt2 * 16 + lr;
#pragma unroll
      for (int j = 0; j < 4; ++j) {
        const int row = rowb + mt * 16 + lc * 4 + j;
        float v = acc[mt][nt2][j];
        if (mode == 0) {
          Of[obase + (size_t)row * N + col] = v;
        } else if (mode == 1) {
          float mv = br ? mask1[row] : mask0[row];
          Of[obase + (size_t)row * N + col] = (v + bias[col]) * mv;
        } else {
          Ob[obase + (size_t)row * N + col] = f2bf(v * oscale);
        }
      }
    }
}

// ==================== LayerNorm -> frag-packed bf16 hi/lo ====================
__global__ __launch_bounds__(256) void ln_split(const float* __restrict__ xr,
                                                const float* __restrict__ bsr,
                                                const float* __restrict__ gamma,
                                                const float* __restrict__ beta,
                                                u16* __restrict__ xnph, u16* __restrict__ xnpl) {
  const int row = blockIdx.x;
  const int br = blockIdx.y;
  const int t = threadIdx.x;
  const float* p = xr + (size_t)br * 2 * 524288 + (size_t)row * 512;
  const int c = t * 2;
  float v0 = p[c] + p[524288 + c] + bsr[c];
  float v1 = p[c + 1] + p[524288 + c + 1] + bsr[c + 1];
  float s = v0 + v1, sq = v0 * v0 + v1 * v1;
#pragma unroll
  for (int m = 1; m < 64; m <<= 1) {
    s += __shfl_xor(s, m, 64);
    sq += __shfl_xor(sq, m, 64);
  }
  __shared__ float ls[4], lsq[4];
  __shared__ float ybuf[512];
  if ((t & 63) == 0) { ls[t >> 6] = s; lsq[t >> 6] = sq; }
  __syncthreads();
  s = ls[0] + ls[1] + ls[2] + ls[3];
  sq = lsq[0] + lsq[1] + lsq[2] + lsq[3];
  float mean = s * (1.0f / 512.0f);
  float var = sq * (1.0f / 512.0f) - mean * mean;
  float rs = rsqrtf(var + 1e-5f);
  ybuf[c] = (v0 - mean) * rs * gamma[c] + beta[c];
  ybuf[c + 1] = (v1 - mean) * rs * gamma[c + 1] + beta[c + 1];
  __syncthreads();
  if (t < 128) {
    const int which = t >> 6, ch = t & 63;
    const int c0 = ch * 8;
    const int kt = c0 >> 5, lcf = (c0 >> 3) & 3, lrf = row & 15;
    const size_t dst = (size_t)br * 524288 +
        ((size_t)(row >> 4) * 16 + kt) * 512 + (lcf * 16 + lrf) * 8;
    short8 o8;
    if (which == 0) {
#pragma unroll
      for (int j = 0; j < 8; ++j) o8[j] = (short)f2bf(ybuf[c0 + j]);
      *(short8*)&xnph[dst] = o8;
    } else {
#pragma unroll
      for (int j = 0; j < 8; ++j) {
        float v = ybuf[c0 + j];
        o8[j] = (short)f2bf(v - bf2f(f2bf(v)));
      }
      *(short8*)&xnpl[dst] = o8;
    }
  }
}

// ==================== pack K and V^T into MFMA A-fragment layout ====================
__global__ __launch_bounds__(256) void kvpack(const u16* __restrict__ kvb,
                                              u16* __restrict__ kf, u16* __restrict__ vf) {
  const int tg = blockIdx.x * 256 + threadIdx.x;   // 2^18 threads
  const int l = tg & 63;
  const int frag = (tg >> 6) & 127;
  const int h = (tg >> 13) & 7;
  const int br = (tg >> 16) & 1;
  const int which = tg >> 17;
  const int lr = l & 15;
  const int lq = l >> 4;
  const size_t dst = (size_t)br * 524288 + (size_t)h * 65536 + (size_t)frag * 512 + l * 8;
  if (which == 0) {
    const int m = (frag >> 1) * 16 + lr;
    const int d = (frag & 1) * 32 + lq * 8;
    short8 v = *(const short8*)&kvb[(size_t)br * 1048576 + (size_t)m * 1024 + h * 64 + d];
    *(short8*)&kf[dst] = v;
  } else {
    const int m = (frag >> 2) * 32 + lq * 8;
    const int d = (frag & 3) * 16 + lr;
    const u16* src = &kvb[(size_t)br * 1048576 + (size_t)m * 1024 + 512 + h * 64 + d];
    short8 v;
#pragma unroll
    for (int j = 0; j < 8; ++j) v[j] = (short)src[(size_t)j * 1024];
    *(short8*)&vf[dst] = v;
  }
}

// ==================== MFMA flash attention (32 q/block, 4-way KV split) ====================
// Output written FRAG-PACKED for the out-proj GEMM (branch stride 2097152).
__global__ __launch_bounds__(256) void attn_mfma(const u16* __restrict__ qb,
                                                 const u16* __restrict__ kf,
                                                 const u16* __restrict__ vf,
                                                 u16* __restrict__ aoph, u16* __restrict__ aopl) {
  const int t = threadIdx.x;
  const int w = t >> 6;
  const int l = t & 63;
  const int lr = l & 15;
  const int lc = l >> 4;
  const int hh = blockIdx.y;
  const int n0 = blockIdx.x * 32;
  const int br = blockIdx.z;
  qb += (size_t)br * 2097152;
  kf += (size_t)br * 524288 + (size_t)hh * 65536;
  vf += (size_t)br * 524288 + (size_t)hh * 65536;
  aoph += (size_t)br * 2097152;
  aopl += (size_t)br * 2097152;

  __shared__ __align__(16) u16 Pl[4][2304];   // per-wave P^T: [32 q][72 kv]
  __shared__ float Osum[4][64][33];           // per-wave O^T partial [d][q]
  __shared__ float Lsum[4][32];
  u16* Pw = &Pl[w][0];

  short8 bq[2][2];
#pragma unroll
  for (int qh = 0; qh < 2; ++qh) {
    const size_t qrow = (size_t)(n0 + qh * 16 + lr) * 512 + hh * 64;
    bq[qh][0] = *(const short8*)&qb[qrow + lc * 8];
    bq[qh][1] = *(const short8*)&qb[qrow + 32 + lc * 8];
  }

  f32x4 acc[4][2];   // [db][qh]
#pragma unroll
  for (int a = 0; a < 4; ++a)
#pragma unroll
    for (int b = 0; b < 2; ++b) acc[a][b] = (f32x4){0.f, 0.f, 0.f, 0.f};
  float lsum0 = 0.f, lsum1 = 0.f;

  for (int it = 0; it < 4; ++it) {
    const int m0 = w * 256 + it * 64;

    const u16* ktile = kf + (size_t)(m0 >> 4) * 1024;
    const u16* vtile = vf + (size_t)(m0 >> 5) * 2048;
    short8 kc[8], av[8];
#pragma unroll
    for (int f = 0; f < 8; ++f)
      kc[f] = *(const short8*)&ktile[(size_t)f * 512 + l * 8];
#pragma unroll
    for (int f = 0; f < 8; ++f)
      av[f] = *(const short8*)&vtile[(size_t)f * 512 + l * 8];

#pragma unroll
    for (int f = 0; f < 4; ++f) {
      f32x4 st0 = (f32x4){0.f, 0.f, 0.f, 0.f};
      f32x4 st1 = (f32x4){0.f, 0.f, 0.f, 0.f};
      __builtin_amdgcn_s_setprio(1);
      st0 = __builtin_amdgcn_mfma_f32_16x16x32_bf16(kc[f * 2 + 0], bq[0][0], st0, 0, 0, 0);
      st0 = __builtin_amdgcn_mfma_f32_16x16x32_bf16(kc[f * 2 + 1], bq[0][1], st0, 0, 0, 0);
      st1 = __builtin_amdgcn_mfma_f32_16x16x32_bf16(kc[f * 2 + 0], bq[1][0], st1, 0, 0, 0);
      st1 = __builtin_amdgcn_mfma_f32_16x16x32_bf16(kc[f * 2 + 1], bq[1][1], st1, 0, 0, 0);
      __builtin_amdgcn_s_setprio(0);
      float p0, p1, p2, p3;
      asm("v_exp_f32 %0, %1" : "=v"(p0) : "v"(st0[0]));
      asm("v_exp_f32 %0, %1" : "=v"(p1) : "v"(st0[1]));
      asm("v_exp_f32 %0, %1" : "=v"(p2) : "v"(st0[2]));
      asm("v_exp_f32 %0, %1" : "=v"(p3) : "v"(st0[3]));
      lsum0 += (p0 + p1) + (p2 + p3);
      u32 pa, pb;
      asm("v_cvt_pk_bf16_f32 %0, %1, %2" : "=v"(pa) : "v"(p0), "v"(p1));
      asm("v_cvt_pk_bf16_f32 %0, %1, %2" : "=v"(pb) : "v"(p2), "v"(p3));
      uint2 pk0; pk0.x = pa; pk0.y = pb;
      *(uint2*)&Pw[lr * 72 + f * 16 + lc * 4] = pk0;
      asm("v_exp_f32 %0, %1" : "=v"(p0) : "v"(st1[0]));
      asm("v_exp_f32 %0, %1" : "=v"(p1) : "v"(st1[1]));
      asm("v_exp_f32 %0, %1" : "=v"(p2) : "v"(st1[2]));
      asm("v_exp_f32 %0, %1" : "=v"(p3) : "v"(st1[3]));
      lsum1 += (p0 + p1) + (p2 + p3);
      asm("v_cvt_pk_bf16_f32 %0, %1, %2" : "=v"(pa) : "v"(p0), "v"(p1));
      asm("v_cvt_pk_bf16_f32 %0, %1, %2" : "=v"(pb) : "v"(p2), "v"(p3));
      uint2 pk1; pk1.x = pa; pk1.y = pb;
      *(uint2*)&Pw[(16 + lr) * 72 + f * 16 + lc * 4] = pk1;
    }

#pragma unroll
    for (int ks = 0; ks < 2; ++ks) {
#pragma unroll
      for (int qh = 0; qh < 2; ++qh) {
        short8 bp = *(const short8*)&Pw[(qh * 16 + lr) * 72 + ks * 32 + lc * 8];
        __builtin_amdgcn_s_setprio(1);
#pragma unroll
        for (int db = 0; db < 4; ++db)
          acc[db][qh] = __builtin_amdgcn_mfma_f32_16x16x32_bf16(av[ks * 4 + db], bp, acc[db][qh], 0, 0, 0);
        __builtin_amdgcn_s_setprio(0);
      }
    }
  }

  lsum0 += __shfl_xor(lsum0, 16, 64);
  lsum0 += __shfl_xor(lsum0, 32, 64);
  lsum1 += __shfl_xor(lsum1, 16, 64);
  lsum1 += __shfl_xor(lsum1, 32, 64);
#pragma unroll
  for (int db = 0; db < 4; ++db)
#pragma unroll
    for (int qh = 0; qh < 2; ++qh)
#pragma unroll
      for (int j = 0; j < 4; ++j)
        Osum[w][db * 16 + lc * 4 + j][qh * 16 + lr] = acc[db][qh][j];
  if (lc == 0) { Lsum[w][lr] = lsum0; Lsum[w][16 + lr] = lsum1; }
  __syncthreads();

  // combine wave partials, normalize, write FRAG-PACKED hi/lo
  const int q = t & 31;
  const int d0 = (t >> 5) * 8;
  const float linv = 1.0f / (Lsum[0][q] + Lsum[1][q] + Lsum[2][q] + Lsum[3][q]);
  short8 hv, lv;
#pragma unroll
  for (int i = 0; i < 8; ++i) {
    const int d = d0 + i;
    float v = (Osum[0][d][q] + Osum[1][d][q] + Osum[2][d][q] + Osum[3][d][q]) * linv;
    u16 hi = f2bf(v);
    hv[i] = (short)hi;
    lv[i] = (short)f2bf(v - bf2f(hi));
  }
  const int mrow = n0 + q;
  const int kcoord = hh * 64 + d0;
  const size_t dst = ((size_t)(mrow >> 4) * 16 + (kcoord >> 5)) * 512 +
                     (((kcoord >> 3) & 3) * 16 + (mrow & 15)) * 8;
  *(short8*)&aoph[dst] = hv;
  *(short8*)&aopl[dst] = lv;
}

// ==================== token exchange ====================
__global__ __launch_bounds__(256) void exchange_f32(float* __restrict__ out,
                                                    const float* __restrict__ mask0,
                                                    const float* __restrict__ mask1) {
  int idx = blockIdx.x * 256 + threadIdx.x;
  int n = idx >> 9;
  float o0 = out[idx];
  float o1 = out[idx + NTOK * CDIM];
  bool k0 = mask0[n] >= 0.02f;
  bool k1 = mask1[n] >= 0.02f;
  out[idx] = k0 ? o0 : o1;
  out[idx + NTOK * CDIM] = k1 ? o1 : o0;
}

extern "C" void kernel_launch(void* const* d_in, const int* in_sizes, int n_in,
                              void* d_out, int out_size, void* d_ws, size_t ws_size,
                              hipStream_t stream) {
  const float* x0    = (const float*)d_in[0];
  const float* x1    = (const float*)d_in[1];
  const float* mask0 = (const float*)d_in[2];
  const float* mask1 = (const float*)d_in[3];
  const float* Wq    = (const float*)d_in[4];
  const float* Wkv   = (const float*)d_in[5];
  const float* Wsr   = (const float*)d_in[6];
  const float* bsr   = (const float*)d_in[7];
  const float* gamma = (const float*)d_in[8];
  const float* beta  = (const float*)d_in[9];
  const float* Wp    = (const float*)d_in[10];
  const float* bp    = (const float*)d_in[11];

  u16* U = (u16*)d_ws;
  u16* WqTph  = U;                    // 262144
  u16* WqTpl  = WqTph + 262144;
  u16* WkvTph = WqTpl + 262144;       // 524288
  u16* WkvTpl = WkvTph + 524288;
  u16* WpTph  = WkvTpl + 524288;      // 262144
  u16* WpTpl  = WpTph + 262144;
  u16* W2Tph  = WpTpl + 262144;       // 1048576
  u16* W2Tpl  = W2Tph + 1048576;
  u16* xqh    = W2Tpl + 1048576;      // 4194304 (2 br, stride 2097152)
  u16* xql    = xqh + 4194304;
  u16* XC     = xql + 4194304;        // 8388608 region
  u16* xch    = XC;                   // 4194304 (2 br)
  u16* xcl    = XC + 4194304;
  // aliases into XC after conv consumes xc:
  u16* qb2    = XC;                   // 4194304
  u16* kvb    = XC + 4194304;         // 2097152
  u16* xnph   = XC + 6291456;         // 1048576 (2 br, stride 524288)
  u16* xnpl   = XC + 7340032;         // 1048576
  float* xr   = (float*)(XC + 8388608);  // 2097152 f32 (2 br x 2 parts)
  u16* kf     = (u16*)xr;             // alias after ln: 1048576
  u16* vf     = kf + 1048576;         // 1048576
  // aop aliases xq after q-proj:
  u16* aoph   = xqh;                  // 2 br, stride 2097152
  u16* aopl   = xql;

  float* out = (float*)d_out;
  dim3 blk(256);

  // fragment-packing prep (weights + x in q-proj and conv-gather orders)
  prep_pack<<<5120, blk, 0, stream>>>(Wq, Wkv, Wp, Wsr, x0, x1,
      WqTph, WqTpl, WkvTph, WkvTpl, WpTph, WpTpl, W2Tph, W2Tpl,
      xqh, xql, xch, xcl);

  // SR conv as packed GEMM, split-K=2 -> f32 partials (runs first: frees xc)
  gemm_sp<<<dim3(8, 16, 4), blk, 0, stream>>>(xch, xcl, xch + 2097152, xcl + 2097152,
      W2Tph, W2Tpl, 1024, 512, 64, 32, 2, 0, xr, nullptr, nullptr, nullptr, nullptr, 1.0f);

  // LayerNorm (+bsr) -> frag-packed bf16
  ln_split<<<dim3(1024, 2), blk, 0, stream>>>(xr, bsr, gamma, beta, xnph, xnpl);

  // q projection -> bf16 q row-major, pre-scaled by hd^-0.5 * log2(e)
  gemm_sp<<<dim3(8, 64, 2), blk, 0, stream>>>(xqh, xql, xqh + 2097152, xql + 2097152,
      WqTph, WqTpl, 4096, 512, 16, 16, 1, 2, nullptr, qb2, nullptr, nullptr, nullptr,
      0.125f * 1.4426950408889634f);

  // kv projection -> bf16 kv row-major
  gemm_sp<<<dim3(16, 16, 2), blk, 0, stream>>>(xnph, xnpl, xnph + 524288, xnpl + 524288,
      WkvTph, WkvTpl, 1024, 1024, 16, 16, 1, 2, nullptr, kvb, nullptr, nullptr, nullptr, 1.0f);

  // pack K and V^T into MFMA fragment layout
  kvpack<<<1024, blk, 0, stream>>>(kvb, kf, vf);

  // attention -> ao frag-packed hi/lo
  attn_mfma<<<dim3(128, 8, 2), blk, 0, stream>>>(qb2, kf, vf, aoph, aopl);

  // output projection + bias + mask -> f32 out
  gemm_sp<<<dim3(8, 64, 2), blk, 0, stream>>>(aoph, aopl, aoph + 2097152, aopl + 2097152,
      WpTph, WpTpl, 4096, 512, 16, 16, 1, 1, out, nullptr, bp, mask0, mask1, 1.0f);

  // token exchange
  exchange_f32<<<8192, blk, 0, stream>>>(out, mask0, mask1);
}

// Round 10
// 135.622 us; speedup vs baseline: 1.1315x; 1.1315x over previous
//
#include <hip/hip_runtime.h>
#include <math.h>

typedef unsigned short u16;
typedef unsigned int u32;
typedef unsigned long long u64;
typedef __attribute__((ext_vector_type(8))) short short8;
typedef __attribute__((ext_vector_type(4))) float f32x4;

#define CDIM 512
#define NTOK 4096
#define MTOK 1024
#define NHEAD 8

// ---------- bf16 helpers ----------
__device__ __forceinline__ u16 f2bf(float x) {
  u32 b = __float_as_uint(x);
  u32 r = (b + 0x7FFFu + ((b >> 16) & 1u)) >> 16;
  return (u16)r;
}
__device__ __forceinline__ float bf2f(u16 u) {
  return __uint_as_float(((u32)u) << 16);
}

__device__ __forceinline__ void gload16(const void* g, void* l) {
  __builtin_amdgcn_global_load_lds(
      (const __attribute__((address_space(1))) u32*)g,
      (__attribute__((address_space(3))) u32*)l, 16, 0, 0);
}

// ==================== fragment-packing prep ====================
// Frag layout (1024 B each): packed[frag*512 + l*8 + j] =
//   Mat[mt*16 + (l&15)][kt*32 + (l>>4)*8 + j],  frag = mt*Kf + kt.
__global__ __launch_bounds__(256) void prep_pack(
    const float* __restrict__ Wq, const float* __restrict__ Wkv,
    const float* __restrict__ Wp, const float* __restrict__ Wsr,
    const float* __restrict__ x0, const float* __restrict__ x1,
    u16* __restrict__ WqTph, u16* __restrict__ WqTpl,
    u16* __restrict__ WkvTph, u16* __restrict__ WkvTpl,
    u16* __restrict__ WpTph, u16* __restrict__ WpTpl,
    u16* __restrict__ W2Tph, u16* __restrict__ W2Tpl,
    u16* __restrict__ xqh, u16* __restrict__ xql,
    u16* __restrict__ xch, u16* __restrict__ xcl) {
  const int b = blockIdx.x, t = threadIdx.x;
  const int fid = t >> 6, l = t & 63, lr = l & 15, lc = l >> 4;
  float v[8];
  u16* dh; u16* dl; size_t dst;
  if (b < 512) {
    const float* W; u16 *oh, *ol; int N, f;
    if (b < 128)      { W = Wq;  oh = WqTph;  ol = WqTpl;  N = 512;  f = b * 4 + fid; }
    else if (b < 384) { W = Wkv; oh = WkvTph; ol = WkvTpl; N = 1024; f = (b - 128) * 4 + fid; }
    else              { W = Wp;  oh = WpTph;  ol = WpTpl;  N = 512;  f = (b - 384) * 4 + fid; }
    const int nt = f >> 4, kt = f & 15;
    const int n = nt * 16 + lr, k0 = kt * 32 + lc * 8;
#pragma unroll
    for (int j = 0; j < 8; ++j) v[j] = W[(size_t)(k0 + j) * N + n];
    dh = oh; dl = ol; dst = (size_t)f * 512 + l * 8;
  } else if (b < 1024) {
    const int f = (b - 512) * 4 + fid;          // ot*64 + kt (2048 frags)
    const int ot = f >> 6, kt = f & 63;
    const int o = ot * 16 + lr;
    const int r0 = kt * 32 + lc * 8;
    const int p = r0 >> 9, i0 = r0 & 511;
#pragma unroll
    for (int j = 0; j < 8; ++j) v[j] = Wsr[(size_t)o * 2048 + (size_t)(i0 + j) * 4 + p];
    dh = W2Tph; dl = W2Tpl; dst = (size_t)f * 512 + l * 8;
  } else if (b < 3072) {
    const int g = (b - 1024) * 4 + fid;         // br(2) x mt(256) x kt(16)
    const int br = g >> 12, fl = g & 4095;
    const int mt = fl >> 4, kt = fl & 15;
    const float* x = br ? x1 : x0;
    const float* src = x + (size_t)(mt * 16 + lr) * 512 + kt * 32 + lc * 8;
#pragma unroll
    for (int j = 0; j < 8; ++j) v[j] = src[j];
    dh = xqh; dl = xql; dst = (size_t)br * 2097152 + (size_t)fl * 512 + l * 8;
  } else {
    const int g = (b - 3072) * 4 + fid;         // br(2) x mt(64) x kt(64)
    const int br = g >> 12, fl = g & 4095;
    const int mt = fl >> 6, kt = fl & 63;
    const int m = mt * 16 + lr;
    const int p = kt >> 4, i0 = (kt * 32 + lc * 8) & 511;
    const int token = (((m >> 5) * 2 + (p >> 1)) << 6) + ((m & 31) * 2 + (p & 1));
    const float* x = br ? x1 : x0;
    const float* src = x + (size_t)token * 512 + i0;
#pragma unroll
    for (int j = 0; j < 8; ++j) v[j] = src[j];
    dh = xch; dl = xcl; dst = (size_t)br * 2097152 + (size_t)fl * 512 + l * 8;
  }
  short8 hv, lv;
#pragma unroll
  for (int j = 0; j < 8; ++j) {
    u16 hi = f2bf(v[j]);
    hv[j] = (short)hi;
    lv[j] = (short)f2bf(v[j] - bf2f(hi));
  }
  *(short8*)&dh[dst] = hv;
  *(short8*)&dl[dst] = lv;
}

// ==================== split-bf16 MFMA GEMM (frag-packed, 2-buf dbuf) ====================
// A/B: frag-packed, Kf frags per row-frag. ktiles K-steps starting at kcid*ktiles.
// modes: 0 = f32 at Of + bz*M*N; 2 = bf16(acc*oscale) row-major at Ob + br*M*N.
__global__ __launch_bounds__(256) void gemm_sp(
    const u16* __restrict__ A0h, const u16* __restrict__ A0l,
    const u16* __restrict__ A1h, const u16* __restrict__ A1l,
    const u16* __restrict__ BTh, const u16* __restrict__ BTl,
    int M, int N, int Kf, int ktiles, int nk, int mode,
    float* __restrict__ Of, u16* __restrict__ Ob,
    float oscale) {
  const int t = threadIdx.x;
  const int w = t >> 6;
  const int l = t & 63;
  const int lr = l & 15;
  const int lc = l >> 4;

  // bijective XCD-chunk swizzle (all grids have total % 8 == 0)
  const int nwx = gridDim.x, nwy = gridDim.y;
  const int total = nwx * nwy * gridDim.z;
  const int L = blockIdx.x + nwx * (blockIdx.y + nwy * blockIdx.z);
  const int chunk = total >> 3;
  int W = (L & 7) * chunk + (L >> 3);
  const int wx = W % nwx; W /= nwx;
  const int wy = W % nwy;
  const int bz = W / nwy;

  const int br = bz / nk, kcid = bz % nk;
  const int row0 = wy * 64;
  const int col0 = wx * 64;
  const u16* Ah = br ? A1h : A0h;
  const u16* Al = br ? A1l : A0l;

  const size_t abase = (size_t)((row0 >> 4) + w) * Kf * 512 + (size_t)l * 8;
  const size_t bbase = (size_t)((col0 >> 4) + w) * Kf * 512 + (size_t)l * 8;

  __shared__ u16 sAh[2][2048], sAl[2][2048], sBh[2][2048], sBl[2][2048];

  auto stage = [&](int buf, int kt) {
    gload16(Ah + abase + (size_t)kt * 512, (void*)&sAh[buf][w * 512]);
    gload16(Al + abase + (size_t)kt * 512, (void*)&sAl[buf][w * 512]);
    gload16(BTh + bbase + (size_t)kt * 512, (void*)&sBh[buf][w * 512]);
    gload16(BTl + bbase + (size_t)kt * 512, (void*)&sBl[buf][w * 512]);
  };

  f32x4 acc[2][2];
#pragma unroll
  for (int a = 0; a < 2; ++a)
#pragma unroll
    for (int b2 = 0; b2 < 2; ++b2) acc[a][b2] = (f32x4){0.f, 0.f, 0.f, 0.f};

  const int kt0 = kcid * ktiles;
  const int wr = (w >> 1) * 2;
  const int wc = (w & 1) * 2;

  stage(0, kt0);
  __syncthreads();

  int cur = 0;
  for (int ti = 0; ti < ktiles; ++ti) {
    if (ti + 1 < ktiles) stage(cur ^ 1, kt0 + ti + 1);

    short8 ah[2], al[2], bh[2], bl[2];
#pragma unroll
    for (int i = 0; i < 2; ++i) {
      ah[i] = *(const short8*)&sAh[cur][(wr + i) * 512 + l * 8];
      al[i] = *(const short8*)&sAl[cur][(wr + i) * 512 + l * 8];
      bh[i] = *(const short8*)&sBh[cur][(wc + i) * 512 + l * 8];
      bl[i] = *(const short8*)&sBl[cur][(wc + i) * 512 + l * 8];
    }
#pragma unroll
    for (int mt = 0; mt < 2; ++mt)
#pragma unroll
      for (int nt2 = 0; nt2 < 2; ++nt2) {
        acc[mt][nt2] = __builtin_amdgcn_mfma_f32_16x16x32_bf16(ah[mt], bh[nt2], acc[mt][nt2], 0, 0, 0);
        acc[mt][nt2] = __builtin_amdgcn_mfma_f32_16x16x32_bf16(ah[mt], bl[nt2], acc[mt][nt2], 0, 0, 0);
        acc[mt][nt2] = __builtin_amdgcn_mfma_f32_16x16x32_bf16(al[mt], bh[nt2], acc[mt][nt2], 0, 0, 0);
      }
    __syncthreads();
    cur ^= 1;
  }

  const int rowb = row0 + (w >> 1) * 32;
  const int colb = col0 + (w & 1) * 32;
  const size_t obase = (mode == 0) ? (size_t)bz * M * N : (size_t)br * M * N;
#pragma unroll
  for (int mt = 0; mt < 2; ++mt)
#pragma unroll
    for (int nt2 = 0; nt2 < 2; ++nt2) {
      const int col = colb + nt2 * 16 + lr;
#pragma unroll
      for (int j = 0; j < 4; ++j) {
        const int row = rowb + mt * 16 + lc * 4 + j;
        float v = acc[mt][nt2][j];
        if (mode == 0) {
          Of[obase + (size_t)row * N + col] = v;
        } else {
          Ob[obase + (size_t)row * N + col] = f2bf(v * oscale);
        }
      }
    }
}

// ==================== fused out-proj + bias + mask + token exchange ====================
// Both branches per block (Wp shared). A frag-packed (branch stride 2097152).
// out[row][col] and out[2097152 + ...] written once, final.
__global__ __launch_bounds__(256) void gemm_out(
    const u16* __restrict__ Aph, const u16* __restrict__ Apl,
    const u16* __restrict__ Bh, const u16* __restrict__ Bl,
    const float* __restrict__ bias,
    const float* __restrict__ mask0, const float* __restrict__ mask1,
    float* __restrict__ out) {
  const int t = threadIdx.x;
  const int w = t >> 6;
  const int l = t & 63;
  const int lr = l & 15;
  const int lc = l >> 4;

  // XCD swizzle over (8, 64) = 512 blocks
  const int nwx = gridDim.x;
  const int total = nwx * gridDim.y;
  const int L = blockIdx.x + nwx * blockIdx.y;
  const int chunk = total >> 3;
  int W = (L & 7) * chunk + (L >> 3);
  const int wx = W % nwx;
  const int wy = W / nwx;

  const int row0 = wy * 64;
  const int col0 = wx * 64;
  const int Kf = 16;

  const size_t abase = (size_t)((row0 >> 4) + w) * Kf * 512 + (size_t)l * 8;
  const size_t bbase = (size_t)((col0 >> 4) + w) * Kf * 512 + (size_t)l * 8;

  __shared__ u16 sA0h[2][2048], sA0l[2][2048], sA1h[2][2048], sA1l[2][2048];
  __shared__ u16 sBh[2][2048], sBl[2][2048];

  auto stage = [&](int buf, int kt) {
    const size_t ao = abase + (size_t)kt * 512;
    gload16(Aph + ao, (void*)&sA0h[buf][w * 512]);
    gload16(Apl + ao, (void*)&sA0l[buf][w * 512]);
    gload16(Aph + 2097152 + ao, (void*)&sA1h[buf][w * 512]);
    gload16(Apl + 2097152 + ao, (void*)&sA1l[buf][w * 512]);
    const size_t bo = bbase + (size_t)kt * 512;
    gload16(Bh + bo, (void*)&sBh[buf][w * 512]);
    gload16(Bl + bo, (void*)&sBl[buf][w * 512]);
  };

  f32x4 acc0[2][2], acc1[2][2];
#pragma unroll
  for (int a = 0; a < 2; ++a)
#pragma unroll
    for (int b2 = 0; b2 < 2; ++b2) {
      acc0[a][b2] = (f32x4){0.f, 0.f, 0.f, 0.f};
      acc1[a][b2] = (f32x4){0.f, 0.f, 0.f, 0.f};
    }

  const int wr = (w >> 1) * 2;
  const int wc = (w & 1) * 2;

  stage(0, 0);
  __syncthreads();

  int cur = 0;
  for (int ti = 0; ti < 16; ++ti) {
    if (ti + 1 < 16) stage(cur ^ 1, ti + 1);

    short8 a0h[2], a0l[2], a1h[2], a1l[2], bh[2], bl[2];
#pragma unroll
    for (int i = 0; i < 2; ++i) {
      a0h[i] = *(const short8*)&sA0h[cur][(wr + i) * 512 + l * 8];
      a0l[i] = *(const short8*)&sA0l[cur][(wr + i) * 512 + l * 8];
      a1h[i] = *(const short8*)&sA1h[cur][(wr + i) * 512 + l * 8];
      a1l[i] = *(const short8*)&sA1l[cur][(wr + i) * 512 + l * 8];
      bh[i] = *(const short8*)&sBh[cur][(wc + i) * 512 + l * 8];
      bl[i] = *(const short8*)&sBl[cur][(wc + i) * 512 + l * 8];
    }
#pragma unroll
    for (int mt = 0; mt < 2; ++mt)
#pragma unroll
      for (int nt2 = 0; nt2 < 2; ++nt2) {
        acc0[mt][nt2] = __builtin_amdgcn_mfma_f32_16x16x32_bf16(a0h[mt], bh[nt2], acc0[mt][nt2], 0, 0, 0);
        acc0[mt][nt2] = __builtin_amdgcn_mfma_f32_16x16x32_bf16(a0h[mt], bl[nt2], acc0[mt][nt2], 0, 0, 0);
        acc0[mt][nt2] = __builtin_amdgcn_mfma_f32_16x16x32_bf16(a0l[mt], bh[nt2], acc0[mt][nt2], 0, 0, 0);
        acc1[mt][nt2] = __builtin_amdgcn_mfma_f32_16x16x32_bf16(a1h[mt], bh[nt2], acc1[mt][nt2], 0, 0, 0);
        acc1[mt][nt2] = __builtin_amdgcn_mfma_f32_16x16x32_bf16(a1h[mt], bl[nt2], acc1[mt][nt2], 0, 0, 0);
        acc1[mt][nt2] = __builtin_amdgcn_mfma_f32_16x16x32_bf16(a1l[mt], bh[nt2], acc1[mt][nt2], 0, 0, 0);
      }
    __syncthreads();
    cur ^= 1;
  }

  const int rowb = row0 + (w >> 1) * 32;
  const int colb = col0 + (w & 1) * 32;
#pragma unroll
  for (int mt = 0; mt < 2; ++mt)
#pragma unroll
    for (int nt2 = 0; nt2 < 2; ++nt2) {
      const int col = colb + nt2 * 16 + lr;
      const float bv = bias[col];
#pragma unroll
      for (int j = 0; j < 4; ++j) {
        const int row = rowb + mt * 16 + lc * 4 + j;
        const float m0 = mask0[row], m1 = mask1[row];
        const float o0 = (acc0[mt][nt2][j] + bv) * m0;
        const float o1 = (acc1[mt][nt2][j] + bv) * m1;
        const bool k0 = m0 >= 0.02f, k1 = m1 >= 0.02f;
        out[(size_t)row * 512 + col] = k0 ? o0 : o1;
        out[2097152 + (size_t)row * 512 + col] = k1 ? o1 : o0;
      }
    }
}

// ==================== LayerNorm -> frag-packed bf16 hi/lo ====================
__global__ __launch_bounds__(256) void ln_split(const float* __restrict__ xr,
                                                const float* __restrict__ bsr,
                                                const float* __restrict__ gamma,
                                                const float* __restrict__ beta,
                                                u16* __restrict__ xnph, u16* __restrict__ xnpl) {
  const int row = blockIdx.x;
  const int br = blockIdx.y;
  const int t = threadIdx.x;
  const float* p = xr + (size_t)br * 2 * 524288 + (size_t)row * 512;
  const int c = t * 2;
  float v0 = p[c] + p[524288 + c] + bsr[c];
  float v1 = p[c + 1] + p[524288 + c + 1] + bsr[c + 1];
  float s = v0 + v1, sq = v0 * v0 + v1 * v1;
#pragma unroll
  for (int m = 1; m < 64; m <<= 1) {
    s += __shfl_xor(s, m, 64);
    sq += __shfl_xor(sq, m, 64);
  }
  __shared__ float ls[4], lsq[4];
  __shared__ float ybuf[512];
  if ((t & 63) == 0) { ls[t >> 6] = s; lsq[t >> 6] = sq; }
  __syncthreads();
  s = ls[0] + ls[1] + ls[2] + ls[3];
  sq = lsq[0] + lsq[1] + lsq[2] + lsq[3];
  float mean = s * (1.0f / 512.0f);
  float var = sq * (1.0f / 512.0f) - mean * mean;
  float rs = rsqrtf(var + 1e-5f);
  ybuf[c] = (v0 - mean) * rs * gamma[c] + beta[c];
  ybuf[c + 1] = (v1 - mean) * rs * gamma[c + 1] + beta[c + 1];
  __syncthreads();
  if (t < 128) {
    const int which = t >> 6, ch = t & 63;
    const int c0 = ch * 8;
    const int kt = c0 >> 5, lcf = (c0 >> 3) & 3, lrf = row & 15;
    const size_t dst = (size_t)br * 524288 +
        ((size_t)(row >> 4) * 16 + kt) * 512 + (lcf * 16 + lrf) * 8;
    short8 o8;
    if (which == 0) {
#pragma unroll
      for (int j = 0; j < 8; ++j) o8[j] = (short)f2bf(ybuf[c0 + j]);
      *(short8*)&xnph[dst] = o8;
    } else {
#pragma unroll
      for (int j = 0; j < 8; ++j) {
        float v = ybuf[c0 + j];
        o8[j] = (short)f2bf(v - bf2f(f2bf(v)));
      }
      *(short8*)&xnpl[dst] = o8;
    }
  }
}

// ==================== pack K and V^T into MFMA A-fragment layout ====================
__global__ __launch_bounds__(256) void kvpack(const u16* __restrict__ kvb,
                                              u16* __restrict__ kf, u16* __restrict__ vf) {
  const int tg = blockIdx.x * 256 + threadIdx.x;   // 2^18 threads
  const int l = tg & 63;
  const int frag = (tg >> 6) & 127;
  const int h = (tg >> 13) & 7;
  const int br = (tg >> 16) & 1;
  const int which = tg >> 17;
  const int lr = l & 15;
  const int lq = l >> 4;
  const size_t dst = (size_t)br * 524288 + (size_t)h * 65536 + (size_t)frag * 512 + l * 8;
  if (which == 0) {
    const int m = (frag >> 1) * 16 + lr;
    const int d = (frag & 1) * 32 + lq * 8;
    short8 v = *(const short8*)&kvb[(size_t)br * 1048576 + (size_t)m * 1024 + h * 64 + d];
    *(short8*)&kf[dst] = v;
  } else {
    const int m = (frag >> 2) * 32 + lq * 8;
    const int d = (frag & 3) * 16 + lr;
    const u16* src = &kvb[(size_t)br * 1048576 + (size_t)m * 1024 + 512 + h * 64 + d];
    short8 v;
#pragma unroll
    for (int j = 0; j < 8; ++j) v[j] = (short)src[(size_t)j * 1024];
    *(short8*)&vf[dst] = v;
  }
}

// ==================== MFMA flash attention (32 q/block, 4-way KV split) ====================
// Output written FRAG-PACKED for the out-proj GEMM (branch stride 2097152).
__global__ __launch_bounds__(256) void attn_mfma(const u16* __restrict__ qb,
                                                 const u16* __restrict__ kf,
                                                 const u16* __restrict__ vf,
                                                 u16* __restrict__ aoph, u16* __restrict__ aopl) {
  const int t = threadIdx.x;
  const int w = t >> 6;
  const int l = t & 63;
  const int lr = l & 15;
  const int lc = l >> 4;
  const int hh = blockIdx.y;
  const int n0 = blockIdx.x * 32;
  const int br = blockIdx.z;
  qb += (size_t)br * 2097152;
  kf += (size_t)br * 524288 + (size_t)hh * 65536;
  vf += (size_t)br * 524288 + (size_t)hh * 65536;
  aoph += (size_t)br * 2097152;
  aopl += (size_t)br * 2097152;

  __shared__ __align__(16) u16 Pl[4][2304];   // per-wave P^T: [32 q][72 kv]
  __shared__ float Osum[4][64][33];           // per-wave O^T partial [d][q]
  __shared__ float Lsum[4][32];
  u16* Pw = &Pl[w][0];

  short8 bq[2][2];
#pragma unroll
  for (int qh = 0; qh < 2; ++qh) {
    const size_t qrow = (size_t)(n0 + qh * 16 + lr) * 512 + hh * 64;
    bq[qh][0] = *(const short8*)&qb[qrow + lc * 8];
    bq[qh][1] = *(const short8*)&qb[qrow + 32 + lc * 8];
  }

  f32x4 acc[4][2];   // [db][qh]
#pragma unroll
  for (int a = 0; a < 4; ++a)
#pragma unroll
    for (int b = 0; b < 2; ++b) acc[a][b] = (f32x4){0.f, 0.f, 0.f, 0.f};
  float lsum0 = 0.f, lsum1 = 0.f;

  for (int it = 0; it < 4; ++it) {
    const int m0 = w * 256 + it * 64;

    const u16* ktile = kf + (size_t)(m0 >> 4) * 1024;
    const u16* vtile = vf + (size_t)(m0 >> 5) * 2048;
    short8 kc[8], av[8];
#pragma unroll
    for (int f = 0; f < 8; ++f)
      kc[f] = *(const short8*)&ktile[(size_t)f * 512 + l * 8];
#pragma unroll
    for (int f = 0; f < 8; ++f)
      av[f] = *(const short8*)&vtile[(size_t)f * 512 + l * 8];

#pragma unroll
    for (int f = 0; f < 4; ++f) {
      f32x4 st0 = (f32x4){0.f, 0.f, 0.f, 0.f};
      f32x4 st1 = (f32x4){0.f, 0.f, 0.f, 0.f};
      __builtin_amdgcn_s_setprio(1);
      st0 = __builtin_amdgcn_mfma_f32_16x16x32_bf16(kc[f * 2 + 0], bq[0][0], st0, 0, 0, 0);
      st0 = __builtin_amdgcn_mfma_f32_16x16x32_bf16(kc[f * 2 + 1], bq[0][1], st0, 0, 0, 0);
      st1 = __builtin_amdgcn_mfma_f32_16x16x32_bf16(kc[f * 2 + 0], bq[1][0], st1, 0, 0, 0);
      st1 = __builtin_amdgcn_mfma_f32_16x16x32_bf16(kc[f * 2 + 1], bq[1][1], st1, 0, 0, 0);
      __builtin_amdgcn_s_setprio(0);
      float p0, p1, p2, p3;
      asm("v_exp_f32 %0, %1" : "=v"(p0) : "v"(st0[0]));
      asm("v_exp_f32 %0, %1" : "=v"(p1) : "v"(st0[1]));
      asm("v_exp_f32 %0, %1" : "=v"(p2) : "v"(st0[2]));
      asm("v_exp_f32 %0, %1" : "=v"(p3) : "v"(st0[3]));
      lsum0 += (p0 + p1) + (p2 + p3);
      u32 pa, pb;
      asm("v_cvt_pk_bf16_f32 %0, %1, %2" : "=v"(pa) : "v"(p0), "v"(p1));
      asm("v_cvt_pk_bf16_f32 %0, %1, %2" : "=v"(pb) : "v"(p2), "v"(p3));
      uint2 pk0; pk0.x = pa; pk0.y = pb;
      *(uint2*)&Pw[lr * 72 + f * 16 + lc * 4] = pk0;
      asm("v_exp_f32 %0, %1" : "=v"(p0) : "v"(st1[0]));
      asm("v_exp_f32 %0, %1" : "=v"(p1) : "v"(st1[1]));
      asm("v_exp_f32 %0, %1" : "=v"(p2) : "v"(st1[2]));
      asm("v_exp_f32 %0, %1" : "=v"(p3) : "v"(st1[3]));
      lsum1 += (p0 + p1) + (p2 + p3);
      asm("v_cvt_pk_bf16_f32 %0, %1, %2" : "=v"(pa) : "v"(p0), "v"(p1));
      asm("v_cvt_pk_bf16_f32 %0, %1, %2" : "=v"(pb) : "v"(p2), "v"(p3));
      uint2 pk1; pk1.x = pa; pk1.y = pb;
      *(uint2*)&Pw[(16 + lr) * 72 + f * 16 + lc * 4] = pk1;
    }

#pragma unroll
    for (int ks = 0; ks < 2; ++ks) {
#pragma unroll
      for (int qh = 0; qh < 2; ++qh) {
        short8 bp = *(const short8*)&Pw[(qh * 16 + lr) * 72 + ks * 32 + lc * 8];
        __builtin_amdgcn_s_setprio(1);
#pragma unroll
        for (int db = 0; db < 4; ++db)
          acc[db][qh] = __builtin_amdgcn_mfma_f32_16x16x32_bf16(av[ks * 4 + db], bp, acc[db][qh], 0, 0, 0);
        __builtin_amdgcn_s_setprio(0);
      }
    }
  }

  lsum0 += __shfl_xor(lsum0, 16, 64);
  lsum0 += __shfl_xor(lsum0, 32, 64);
  lsum1 += __shfl_xor(lsum1, 16, 64);
  lsum1 += __shfl_xor(lsum1, 32, 64);
#pragma unroll
  for (int db = 0; db < 4; ++db)
#pragma unroll
    for (int qh = 0; qh < 2; ++qh)
#pragma unroll
      for (int j = 0; j < 4; ++j)
        Osum[w][db * 16 + lc * 4 + j][qh * 16 + lr] = acc[db][qh][j];
  if (lc == 0) { Lsum[w][lr] = lsum0; Lsum[w][16 + lr] = lsum1; }
  __syncthreads();

  // combine wave partials, normalize, write FRAG-PACKED hi/lo
  const int q = t & 31;
  const int d0 = (t >> 5) * 8;
  const float linv = 1.0f / (Lsum[0][q] + Lsum[1][q] + Lsum[2][q] + Lsum[3][q]);
  short8 hv, lv;
#pragma unroll
  for (int i = 0; i < 8; ++i) {
    const int d = d0 + i;
    float v = (Osum[0][d][q] + Osum[1][d][q] + Osum[2][d][q] + Osum[3][d][q]) * linv;
    u16 hi = f2bf(v);
    hv[i] = (short)hi;
    lv[i] = (short)f2bf(v - bf2f(hi));
  }
  const int mrow = n0 + q;
  const int kcoord = hh * 64 + d0;
  const size_t dst = ((size_t)(mrow >> 4) * 16 + (kcoord >> 5)) * 512 +
                     (((kcoord >> 3) & 3) * 16 + (mrow & 15)) * 8;
  *(short8*)&aoph[dst] = hv;
  *(short8*)&aopl[dst] = lv;
}

extern "C" void kernel_launch(void* const* d_in, const int* in_sizes, int n_in,
                              void* d_out, int out_size, void* d_ws, size_t ws_size,
                              hipStream_t stream) {
  const float* x0    = (const float*)d_in[0];
  const float* x1    = (const float*)d_in[1];
  const float* mask0 = (const float*)d_in[2];
  const float* mask1 = (const float*)d_in[3];
  const float* Wq    = (const float*)d_in[4];
  const float* Wkv   = (const float*)d_in[5];
  const float* Wsr   = (const float*)d_in[6];
  const float* bsr   = (const float*)d_in[7];
  const float* gamma = (const float*)d_in[8];
  const float* beta  = (const float*)d_in[9];
  const float* Wp    = (const float*)d_in[10];
  const float* bp    = (const float*)d_in[11];

  u16* U = (u16*)d_ws;
  u16* WqTph  = U;                    // 262144
  u16* WqTpl  = WqTph + 262144;
  u16* WkvTph = WqTpl + 262144;       // 524288
  u16* WkvTpl = WkvTph + 524288;
  u16* WpTph  = WkvTpl + 524288;      // 262144
  u16* WpTpl  = WpTph + 262144;
  u16* W2Tph  = WpTpl + 262144;       // 1048576
  u16* W2Tpl  = W2Tph + 1048576;
  u16* xqh    = W2Tpl + 1048576;      // 4194304 (2 br, stride 2097152)
  u16* xql    = xqh + 4194304;
  u16* XC     = xql + 4194304;        // 8388608 region
  u16* xch    = XC;                   // 4194304 (2 br)
  u16* xcl    = XC + 4194304;
  // aliases into XC after conv consumes xc:
  u16* qb2    = XC;                   // 4194304
  u16* kvb    = XC + 4194304;         // 2097152
  u16* xnph   = XC + 6291456;         // 1048576 (2 br, stride 524288)
  u16* xnpl   = XC + 7340032;         // 1048576
  float* xr   = (float*)(XC + 8388608);  // 2097152 f32 (2 br x 2 parts)
  u16* kf     = (u16*)xr;             // alias after ln: 1048576
  u16* vf     = kf + 1048576;         // 1048576
  // aop aliases xq after q-proj:
  u16* aoph   = xqh;                  // 2 br, stride 2097152
  u16* aopl   = xql;

  float* out = (float*)d_out;
  dim3 blk(256);

  // fragment-packing prep (weights + x in q-proj and conv-gather orders)
  prep_pack<<<5120, blk, 0, stream>>>(Wq, Wkv, Wp, Wsr, x0, x1,
      WqTph, WqTpl, WkvTph, WkvTpl, WpTph, WpTpl, W2Tph, W2Tpl,
      xqh, xql, xch, xcl);

  // SR conv as packed GEMM, split-K=2 -> f32 partials (runs first: frees xc)
  gemm_sp<<<dim3(8, 16, 4), blk, 0, stream>>>(xch, xcl, xch + 2097152, xcl + 2097152,
      W2Tph, W2Tpl, 1024, 512, 64, 32, 2, 0, xr, nullptr, 1.0f);

  // LayerNorm (+bsr) -> frag-packed bf16
  ln_split<<<dim3(1024, 2), blk, 0, stream>>>(xr, bsr, gamma, beta, xnph, xnpl);

  // q projection -> bf16 q row-major, pre-scaled by hd^-0.5 * log2(e)
  gemm_sp<<<dim3(8, 64, 2), blk, 0, stream>>>(xqh, xql, xqh + 2097152, xql + 2097152,
      WqTph, WqTpl, 4096, 512, 16, 16, 1, 2, nullptr, qb2,
      0.125f * 1.4426950408889634f);

  // kv projection -> bf16 kv row-major
  gemm_sp<<<dim3(16, 16, 2), blk, 0, stream>>>(xnph, xnpl, xnph + 524288, xnpl + 524288,
      WkvTph, WkvTpl, 1024, 1024, 16, 16, 1, 2, nullptr, kvb, 1.0f);

  // pack K and V^T into MFMA fragment layout
  kvpack<<<1024, blk, 0, stream>>>(kvb, kf, vf);

  // attention -> ao frag-packed hi/lo
  attn_mfma<<<dim3(128, 8, 2), blk, 0, stream>>>(qb2, kf, vf, aoph, aopl);

  // fused output projection + bias + mask + token exchange -> final out
  gemm_out<<<dim3(8, 64), blk, 0, stream>>>(aoph, aopl, WpTph, WpTpl,
      bp, mask0, mask1, out);
}

// Round 11
// 106.616 us; speedup vs baseline: 1.4393x; 1.2721x over previous
//
#include <hip/hip_runtime.h>
#include <math.h>

typedef unsigned short u16;
typedef unsigned int u32;
typedef unsigned long long u64;
typedef _Float16 f16;
typedef __attribute__((ext_vector_type(8))) _Float16 half8;
typedef __attribute__((ext_vector_type(8))) short short8;
typedef __attribute__((ext_vector_type(4))) float f32x4;

#define CDIM 512
#define NTOK 4096
#define MTOK 1024
#define NHEAD 8

__device__ __forceinline__ u16 f2h(float x) {
  f16 h = (f16)x;
  return *(u16*)&h;
}

__device__ __forceinline__ void gload16(const void* g, void* l) {
  __builtin_amdgcn_global_load_lds(
      (const __attribute__((address_space(1))) u32*)g,
      (__attribute__((address_space(3))) u32*)l, 16, 0, 0);
}

// ==================== fragment-packing prep (fp16, single array) ====================
// Frag (1024 B): packed[frag*512 + l*8 + j] = Mat[mt*16 + (l&15)][kt*32 + (l>>4)*8 + j],
// frag = mt*Kf + kt.
// Blocks: [0,128) WqT; [128,384) WkvT; [384,512) WpT; [512,1024) W2T;
//         [1024,3072) xq; [3072,5120) xc (conv gather order).
__global__ __launch_bounds__(256) void prep_pack(
    const float* __restrict__ Wq, const float* __restrict__ Wkv,
    const float* __restrict__ Wp, const float* __restrict__ Wsr,
    const float* __restrict__ x0, const float* __restrict__ x1,
    u16* __restrict__ WqTp, u16* __restrict__ WkvTp,
    u16* __restrict__ WpTp, u16* __restrict__ W2Tp,
    u16* __restrict__ xq, u16* __restrict__ xc) {
  const int b = blockIdx.x, t = threadIdx.x;
  const int fid = t >> 6, l = t & 63, lr = l & 15, lc = l >> 4;
  float v[8];
  u16* dp; size_t dst;
  if (b < 512) {
    const float* W; u16* op; int N, f;
    if (b < 128)      { W = Wq;  op = WqTp;  N = 512;  f = b * 4 + fid; }
    else if (b < 384) { W = Wkv; op = WkvTp; N = 1024; f = (b - 128) * 4 + fid; }
    else              { W = Wp;  op = WpTp;  N = 512;  f = (b - 384) * 4 + fid; }
    const int nt = f >> 4, kt = f & 15;
    const int n = nt * 16 + lr, k0 = kt * 32 + lc * 8;
#pragma unroll
    for (int j = 0; j < 8; ++j) v[j] = W[(size_t)(k0 + j) * N + n];
    dp = op; dst = (size_t)f * 512 + l * 8;
  } else if (b < 1024) {
    const int f = (b - 512) * 4 + fid;          // ot*64 + kt (2048 frags)
    const int ot = f >> 6, kt = f & 63;
    const int o = ot * 16 + lr;
    const int r0 = kt * 32 + lc * 8;
    const int p = r0 >> 9, i0 = r0 & 511;
#pragma unroll
    for (int j = 0; j < 8; ++j) v[j] = Wsr[(size_t)o * 2048 + (size_t)(i0 + j) * 4 + p];
    dp = W2Tp; dst = (size_t)f * 512 + l * 8;
  } else if (b < 3072) {
    const int g = (b - 1024) * 4 + fid;         // br(2) x mt(256) x kt(16)
    const int br = g >> 12, fl = g & 4095;
    const int mt = fl >> 4, kt = fl & 15;
    const float* x = br ? x1 : x0;
    const float* src = x + (size_t)(mt * 16 + lr) * 512 + kt * 32 + lc * 8;
#pragma unroll
    for (int j = 0; j < 8; ++j) v[j] = src[j];
    dp = xq; dst = (size_t)br * 2097152 + (size_t)fl * 512 + l * 8;
  } else {
    const int g = (b - 3072) * 4 + fid;         // br(2) x mt(64) x kt(64)
    const int br = g >> 12, fl = g & 4095;
    const int mt = fl >> 6, kt = fl & 63;
    const int m = mt * 16 + lr;
    const int p = kt >> 4, i0 = (kt * 32 + lc * 8) & 511;
    const int token = (((m >> 5) * 2 + (p >> 1)) << 6) + ((m & 31) * 2 + (p & 1));
    const float* x = br ? x1 : x0;
    const float* src = x + (size_t)token * 512 + i0;
#pragma unroll
    for (int j = 0; j < 8; ++j) v[j] = src[j];
    dp = xc; dst = (size_t)br * 2097152 + (size_t)fl * 512 + l * 8;
  }
  short8 hv;
#pragma unroll
  for (int j = 0; j < 8; ++j) hv[j] = (short)f2h(v[j]);
  *(short8*)&dp[dst] = hv;
}

// ==================== fp16 MFMA GEMM (frag-packed, 2-buf dbuf) ====================
// modes: 0 = f32 at Of + bz*M*N; 2 = f16(acc*oscale) row-major at Ob + br*M*N.
__global__ __launch_bounds__(256) void gemm_sp(
    const u16* __restrict__ A0, const u16* __restrict__ A1,
    const u16* __restrict__ BT,
    int M, int N, int Kf, int ktiles, int nk, int mode,
    float* __restrict__ Of, u16* __restrict__ Ob, float oscale) {
  const int t = threadIdx.x;
  const int w = t >> 6;
  const int l = t & 63;
  const int lr = l & 15;
  const int lc = l >> 4;

  // bijective XCD-chunk swizzle (all grids have total % 8 == 0)
  const int nwx = gridDim.x, nwy = gridDim.y;
  const int total = nwx * nwy * gridDim.z;
  const int L = blockIdx.x + nwx * (blockIdx.y + nwy * blockIdx.z);
  const int chunk = total >> 3;
  int W = (L & 7) * chunk + (L >> 3);
  const int wx = W % nwx; W /= nwx;
  const int wy = W % nwy;
  const int bz = W / nwy;

  const int br = bz / nk, kcid = bz % nk;
  const int row0 = wy * 64;
  const int col0 = wx * 64;
  const u16* A = br ? A1 : A0;

  const size_t abase = (size_t)((row0 >> 4) + w) * Kf * 512 + (size_t)l * 8;
  const size_t bbase = (size_t)((col0 >> 4) + w) * Kf * 512 + (size_t)l * 8;

  __shared__ u16 sA[2][2048], sB[2][2048];

  auto stage = [&](int buf, int kt) {
    gload16(A + abase + (size_t)kt * 512, (void*)&sA[buf][w * 512]);
    gload16(BT + bbase + (size_t)kt * 512, (void*)&sB[buf][w * 512]);
  };

  f32x4 acc[2][2];
#pragma unroll
  for (int a = 0; a < 2; ++a)
#pragma unroll
    for (int b2 = 0; b2 < 2; ++b2) acc[a][b2] = (f32x4){0.f, 0.f, 0.f, 0.f};

  const int kt0 = kcid * ktiles;
  const int wr = (w >> 1) * 2;
  const int wc = (w & 1) * 2;

  stage(0, kt0);
  __syncthreads();

  int cur = 0;
  for (int ti = 0; ti < ktiles; ++ti) {
    if (ti + 1 < ktiles) stage(cur ^ 1, kt0 + ti + 1);

    half8 a[2], b[2];
#pragma unroll
    for (int i = 0; i < 2; ++i) {
      a[i] = *(const half8*)&sA[cur][(wr + i) * 512 + l * 8];
      b[i] = *(const half8*)&sB[cur][(wc + i) * 512 + l * 8];
    }
#pragma unroll
    for (int mt = 0; mt < 2; ++mt)
#pragma unroll
      for (int nt2 = 0; nt2 < 2; ++nt2)
        acc[mt][nt2] = __builtin_amdgcn_mfma_f32_16x16x32_f16(a[mt], b[nt2], acc[mt][nt2], 0, 0, 0);
    __syncthreads();
    cur ^= 1;
  }

  const int rowb = row0 + (w >> 1) * 32;
  const int colb = col0 + (w & 1) * 32;
  const size_t obase = (mode == 0) ? (size_t)bz * M * N : (size_t)br * M * N;
#pragma unroll
  for (int mt = 0; mt < 2; ++mt)
#pragma unroll
    for (int nt2 = 0; nt2 < 2; ++nt2) {
      const int col = colb + nt2 * 16 + lr;
#pragma unroll
      for (int j = 0; j < 4; ++j) {
        const int row = rowb + mt * 16 + lc * 4 + j;
        float v = acc[mt][nt2][j];
        if (mode == 0) {
          Of[obase + (size_t)row * N + col] = v;
        } else {
          Ob[obase + (size_t)row * N + col] = f2h(v * oscale);
        }
      }
    }
}

// ==================== fused out-proj + bias + mask + token exchange ====================
__global__ __launch_bounds__(256) void gemm_out(
    const u16* __restrict__ Ap, const u16* __restrict__ Bp,
    const float* __restrict__ bias,
    const float* __restrict__ mask0, const float* __restrict__ mask1,
    float* __restrict__ out) {
  const int t = threadIdx.x;
  const int w = t >> 6;
  const int l = t & 63;
  const int lr = l & 15;
  const int lc = l >> 4;

  const int nwx = gridDim.x;
  const int total = nwx * gridDim.y;
  const int L = blockIdx.x + nwx * blockIdx.y;
  const int chunk = total >> 3;
  int W = (L & 7) * chunk + (L >> 3);
  const int wx = W % nwx;
  const int wy = W / nwx;

  const int row0 = wy * 64;
  const int col0 = wx * 64;
  const int Kf = 16;

  const size_t abase = (size_t)((row0 >> 4) + w) * Kf * 512 + (size_t)l * 8;
  const size_t bbase = (size_t)((col0 >> 4) + w) * Kf * 512 + (size_t)l * 8;

  __shared__ u16 sA0[2][2048], sA1[2][2048], sB[2][2048];

  auto stage = [&](int buf, int kt) {
    const size_t ao = abase + (size_t)kt * 512;
    gload16(Ap + ao, (void*)&sA0[buf][w * 512]);
    gload16(Ap + 2097152 + ao, (void*)&sA1[buf][w * 512]);
    gload16(Bp + bbase + (size_t)kt * 512, (void*)&sB[buf][w * 512]);
  };

  f32x4 acc0[2][2], acc1[2][2];
#pragma unroll
  for (int a = 0; a < 2; ++a)
#pragma unroll
    for (int b2 = 0; b2 < 2; ++b2) {
      acc0[a][b2] = (f32x4){0.f, 0.f, 0.f, 0.f};
      acc1[a][b2] = (f32x4){0.f, 0.f, 0.f, 0.f};
    }

  const int wr = (w >> 1) * 2;
  const int wc = (w & 1) * 2;

  stage(0, 0);
  __syncthreads();

  int cur = 0;
  for (int ti = 0; ti < 16; ++ti) {
    if (ti + 1 < 16) stage(cur ^ 1, ti + 1);

    half8 a0[2], a1[2], b[2];
#pragma unroll
    for (int i = 0; i < 2; ++i) {
      a0[i] = *(const half8*)&sA0[cur][(wr + i) * 512 + l * 8];
      a1[i] = *(const half8*)&sA1[cur][(wr + i) * 512 + l * 8];
      b[i] = *(const half8*)&sB[cur][(wc + i) * 512 + l * 8];
    }
#pragma unroll
    for (int mt = 0; mt < 2; ++mt)
#pragma unroll
      for (int nt2 = 0; nt2 < 2; ++nt2) {
        acc0[mt][nt2] = __builtin_amdgcn_mfma_f32_16x16x32_f16(a0[mt], b[nt2], acc0[mt][nt2], 0, 0, 0);
        acc1[mt][nt2] = __builtin_amdgcn_mfma_f32_16x16x32_f16(a1[mt], b[nt2], acc1[mt][nt2], 0, 0, 0);
      }
    __syncthreads();
    cur ^= 1;
  }

  const int rowb = row0 + (w >> 1) * 32;
  const int colb = col0 + (w & 1) * 32;
#pragma unroll
  for (int mt = 0; mt < 2; ++mt)
#pragma unroll
    for (int nt2 = 0; nt2 < 2; ++nt2) {
      const int col = colb + nt2 * 16 + lr;
      const float bv = bias[col];
#pragma unroll
      for (int j = 0; j < 4; ++j) {
        const int row = rowb + mt * 16 + lc * 4 + j;
        const float m0 = mask0[row], m1 = mask1[row];
        const float o0 = (acc0[mt][nt2][j] + bv) * m0;
        const float o1 = (acc1[mt][nt2][j] + bv) * m1;
        const bool k0 = m0 >= 0.02f, k1 = m1 >= 0.02f;
        out[(size_t)row * 512 + col] = k0 ? o0 : o1;
        out[2097152 + (size_t)row * 512 + col] = k1 ? o1 : o0;
      }
    }
}

// ==================== LayerNorm: sum 4 conv partials + bsr -> frag-packed fp16 ====================
__global__ __launch_bounds__(256) void ln_split(const float* __restrict__ xr,
                                                const float* __restrict__ bsr,
                                                const float* __restrict__ gamma,
                                                const float* __restrict__ beta,
                                                u16* __restrict__ xnp) {
  const int row = blockIdx.x;
  const int br = blockIdx.y;
  const int t = threadIdx.x;
  const float* p = xr + (size_t)br * 4 * 524288 + (size_t)row * 512;
  const int c = t * 2;
  float v0 = p[c] + p[524288 + c] + p[1048576 + c] + p[1572864 + c] + bsr[c];
  float v1 = p[c + 1] + p[524288 + c + 1] + p[1048576 + c + 1] + p[1572864 + c + 1] + bsr[c + 1];
  float s = v0 + v1, sq = v0 * v0 + v1 * v1;
#pragma unroll
  for (int m = 1; m < 64; m <<= 1) {
    s += __shfl_xor(s, m, 64);
    sq += __shfl_xor(sq, m, 64);
  }
  __shared__ float ls[4], lsq[4];
  __shared__ float ybuf[512];
  if ((t & 63) == 0) { ls[t >> 6] = s; lsq[t >> 6] = sq; }
  __syncthreads();
  s = ls[0] + ls[1] + ls[2] + ls[3];
  sq = lsq[0] + lsq[1] + lsq[2] + lsq[3];
  float mean = s * (1.0f / 512.0f);
  float var = sq * (1.0f / 512.0f) - mean * mean;
  float rs = rsqrtf(var + 1e-5f);
  ybuf[c] = (v0 - mean) * rs * gamma[c] + beta[c];
  ybuf[c + 1] = (v1 - mean) * rs * gamma[c + 1] + beta[c + 1];
  __syncthreads();
  if (t < 64) {
    const int c0 = t * 8;
    const int kt = c0 >> 5, lcf = (c0 >> 3) & 3, lrf = row & 15;
    const size_t dst = (size_t)br * 524288 +
        ((size_t)(row >> 4) * 16 + kt) * 512 + (lcf * 16 + lrf) * 8;
    short8 o8;
#pragma unroll
    for (int j = 0; j < 8; ++j) o8[j] = (short)f2h(ybuf[c0 + j]);
    *(short8*)&xnp[dst] = o8;
  }
}

// ==================== pack K and V^T into MFMA A-fragment layout ====================
__global__ __launch_bounds__(256) void kvpack(const u16* __restrict__ kvb,
                                              u16* __restrict__ kf, u16* __restrict__ vf) {
  const int tg = blockIdx.x * 256 + threadIdx.x;   // 2^18 threads
  const int l = tg & 63;
  const int frag = (tg >> 6) & 127;
  const int h = (tg >> 13) & 7;
  const int br = (tg >> 16) & 1;
  const int which = tg >> 17;
  const int lr = l & 15;
  const int lq = l >> 4;
  const size_t dst = (size_t)br * 524288 + (size_t)h * 65536 + (size_t)frag * 512 + l * 8;
  if (which == 0) {
    const int m = (frag >> 1) * 16 + lr;
    const int d = (frag & 1) * 32 + lq * 8;
    short8 v = *(const short8*)&kvb[(size_t)br * 1048576 + (size_t)m * 1024 + h * 64 + d];
    *(short8*)&kf[dst] = v;
  } else {
    const int m = (frag >> 2) * 32 + lq * 8;
    const int d = (frag & 3) * 16 + lr;
    const u16* src = &kvb[(size_t)br * 1048576 + (size_t)m * 1024 + 512 + h * 64 + d];
    short8 v;
#pragma unroll
    for (int j = 0; j < 8; ++j) v[j] = (short)src[(size_t)j * 1024];
    *(short8*)&vf[dst] = v;
  }
}

// ==================== fp16 MFMA flash attention (32 q/block, 4-way KV split) ====================
// Output FRAG-PACKED fp16 (branch stride 2097152).
__global__ __launch_bounds__(256) void attn_mfma(const u16* __restrict__ qb,
                                                 const u16* __restrict__ kf,
                                                 const u16* __restrict__ vf,
                                                 u16* __restrict__ aop) {
  const int t = threadIdx.x;
  const int w = t >> 6;
  const int l = t & 63;
  const int lr = l & 15;
  const int lc = l >> 4;
  const int hh = blockIdx.y;
  const int n0 = blockIdx.x * 32;
  const int br = blockIdx.z;
  qb += (size_t)br * 2097152;
  kf += (size_t)br * 524288 + (size_t)hh * 65536;
  vf += (size_t)br * 524288 + (size_t)hh * 65536;
  aop += (size_t)br * 2097152;

  __shared__ __align__(16) u16 Pl[4][2304];   // per-wave P^T: [32 q][72 kv]
  __shared__ float Osum[4][64][33];           // per-wave O^T partial [d][q]
  __shared__ float Lsum[4][32];
  u16* Pw = &Pl[w][0];

  half8 bq[2][2];
#pragma unroll
  for (int qh = 0; qh < 2; ++qh) {
    const size_t qrow = (size_t)(n0 + qh * 16 + lr) * 512 + hh * 64;
    bq[qh][0] = *(const half8*)&qb[qrow + lc * 8];
    bq[qh][1] = *(const half8*)&qb[qrow + 32 + lc * 8];
  }

  f32x4 acc[4][2];   // [db][qh]
#pragma unroll
  for (int a = 0; a < 4; ++a)
#pragma unroll
    for (int b = 0; b < 2; ++b) acc[a][b] = (f32x4){0.f, 0.f, 0.f, 0.f};
  float lsum0 = 0.f, lsum1 = 0.f;

  for (int it = 0; it < 4; ++it) {
    const int m0 = w * 256 + it * 64;

    const u16* ktile = kf + (size_t)(m0 >> 4) * 1024;
    const u16* vtile = vf + (size_t)(m0 >> 5) * 2048;
    half8 kc[8], av[8];
#pragma unroll
    for (int f = 0; f < 8; ++f)
      kc[f] = *(const half8*)&ktile[(size_t)f * 512 + l * 8];
#pragma unroll
    for (int f = 0; f < 8; ++f)
      av[f] = *(const half8*)&vtile[(size_t)f * 512 + l * 8];

#pragma unroll
    for (int f = 0; f < 4; ++f) {
      f32x4 st0 = (f32x4){0.f, 0.f, 0.f, 0.f};
      f32x4 st1 = (f32x4){0.f, 0.f, 0.f, 0.f};
      __builtin_amdgcn_s_setprio(1);
      st0 = __builtin_amdgcn_mfma_f32_16x16x32_f16(kc[f * 2 + 0], bq[0][0], st0, 0, 0, 0);
      st0 = __builtin_amdgcn_mfma_f32_16x16x32_f16(kc[f * 2 + 1], bq[0][1], st0, 0, 0, 0);
      st1 = __builtin_amdgcn_mfma_f32_16x16x32_f16(kc[f * 2 + 0], bq[1][0], st1, 0, 0, 0);
      st1 = __builtin_amdgcn_mfma_f32_16x16x32_f16(kc[f * 2 + 1], bq[1][1], st1, 0, 0, 0);
      __builtin_amdgcn_s_setprio(0);
      float p0, p1, p2, p3;
      asm("v_exp_f32 %0, %1" : "=v"(p0) : "v"(st0[0]));
      asm("v_exp_f32 %0, %1" : "=v"(p1) : "v"(st0[1]));
      asm("v_exp_f32 %0, %1" : "=v"(p2) : "v"(st0[2]));
      asm("v_exp_f32 %0, %1" : "=v"(p3) : "v"(st0[3]));
      lsum0 += (p0 + p1) + (p2 + p3);
      {
        auto ha = __builtin_amdgcn_cvt_pkrtz(p0, p1);
        auto hb = __builtin_amdgcn_cvt_pkrtz(p2, p3);
        uint2 pk; pk.x = __builtin_bit_cast(u32, ha); pk.y = __builtin_bit_cast(u32, hb);
        *(uint2*)&Pw[lr * 72 + f * 16 + lc * 4] = pk;
      }
      asm("v_exp_f32 %0, %1" : "=v"(p0) : "v"(st1[0]));
      asm("v_exp_f32 %0, %1" : "=v"(p1) : "v"(st1[1]));
      asm("v_exp_f32 %0, %1" : "=v"(p2) : "v"(st1[2]));
      asm("v_exp_f32 %0, %1" : "=v"(p3) : "v"(st1[3]));
      lsum1 += (p0 + p1) + (p2 + p3);
      {
        auto ha = __builtin_amdgcn_cvt_pkrtz(p0, p1);
        auto hb = __builtin_amdgcn_cvt_pkrtz(p2, p3);
        uint2 pk; pk.x = __builtin_bit_cast(u32, ha); pk.y = __builtin_bit_cast(u32, hb);
        *(uint2*)&Pw[(16 + lr) * 72 + f * 16 + lc * 4] = pk;
      }
    }

#pragma unroll
    for (int ks = 0; ks < 2; ++ks) {
#pragma unroll
      for (int qh = 0; qh < 2; ++qh) {
        half8 bp = *(const half8*)&Pw[(qh * 16 + lr) * 72 + ks * 32 + lc * 8];
        __builtin_amdgcn_s_setprio(1);
#pragma unroll
        for (int db = 0; db < 4; ++db)
          acc[db][qh] = __builtin_amdgcn_mfma_f32_16x16x32_f16(av[ks * 4 + db], bp, acc[db][qh], 0, 0, 0);
        __builtin_amdgcn_s_setprio(0);
      }
    }
  }

  lsum0 += __shfl_xor(lsum0, 16, 64);
  lsum0 += __shfl_xor(lsum0, 32, 64);
  lsum1 += __shfl_xor(lsum1, 16, 64);
  lsum1 += __shfl_xor(lsum1, 32, 64);
#pragma unroll
  for (int db = 0; db < 4; ++db)
#pragma unroll
    for (int qh = 0; qh < 2; ++qh)
#pragma unroll
      for (int j = 0; j < 4; ++j)
        Osum[w][db * 16 + lc * 4 + j][qh * 16 + lr] = acc[db][qh][j];
  if (lc == 0) { Lsum[w][lr] = lsum0; Lsum[w][16 + lr] = lsum1; }
  __syncthreads();

  // combine wave partials, normalize, write FRAG-PACKED fp16
  const int q = t & 31;
  const int d0 = (t >> 5) * 8;
  const float linv = 1.0f / (Lsum[0][q] + Lsum[1][q] + Lsum[2][q] + Lsum[3][q]);
  short8 hv;
#pragma unroll
  for (int i = 0; i < 8; ++i) {
    const int d = d0 + i;
    float v = (Osum[0][d][q] + Osum[1][d][q] + Osum[2][d][q] + Osum[3][d][q]) * linv;
    hv[i] = (short)f2h(v);
  }
  const int mrow = n0 + q;
  const int kcoord = hh * 64 + d0;
  const size_t dst = ((size_t)(mrow >> 4) * 16 + (kcoord >> 5)) * 512 +
                     (((kcoord >> 3) & 3) * 16 + (mrow & 15)) * 8;
  *(short8*)&aop[dst] = hv;
}

extern "C" void kernel_launch(void* const* d_in, const int* in_sizes, int n_in,
                              void* d_out, int out_size, void* d_ws, size_t ws_size,
                              hipStream_t stream) {
  const float* x0    = (const float*)d_in[0];
  const float* x1    = (const float*)d_in[1];
  const float* mask0 = (const float*)d_in[2];
  const float* mask1 = (const float*)d_in[3];
  const float* Wq    = (const float*)d_in[4];
  const float* Wkv   = (const float*)d_in[5];
  const float* Wsr   = (const float*)d_in[6];
  const float* bsr   = (const float*)d_in[7];
  const float* gamma = (const float*)d_in[8];
  const float* beta  = (const float*)d_in[9];
  const float* Wp    = (const float*)d_in[10];
  const float* bp    = (const float*)d_in[11];

  u16* U = (u16*)d_ws;
  u16* WqTp  = U;                      // 262144
  u16* WkvTp = WqTp + 262144;          // 524288
  u16* WpTp  = WkvTp + 524288;         // 262144
  u16* W2Tp  = WpTp + 262144;          // 1048576
  u16* xq    = W2Tp + 1048576;         // 4194304 (2 br, stride 2097152)
  u16* xc    = xq + 4194304;           // 4194304 (2 br)
  u16* R     = xc + 4194304;           // 8388608 region: xr (f32 4x2x524288) then qb2
  float* xr  = (float*)R;              // 4194304 f32
  u16* qb2   = R;                      // alias: 4194304 (after ln consumes xr)
  u16* kvb   = R + 8388608;            // 2097152
  u16* kf    = kvb + 2097152;          // 1048576
  u16* vf    = kf + 1048576;           // 1048576
  u16* aop   = xq;                     // alias: attn output (xq dead after qproj)

  float* out = (float*)d_out;
  dim3 blk(256);

  // fragment-packing prep (weights + x in q-proj and conv-gather orders)
  prep_pack<<<5120, blk, 0, stream>>>(Wq, Wkv, Wp, Wsr, x0, x1,
      WqTp, WkvTp, WpTp, W2Tp, xq, xc);

  // SR conv as packed GEMM, split-K=4 -> f32 partials
  gemm_sp<<<dim3(8, 16, 8), blk, 0, stream>>>(xc, xc + 2097152, W2Tp,
      1024, 512, 64, 16, 4, 0, xr, nullptr, 1.0f);

  // LayerNorm (+bsr) -> frag-packed fp16 (into kvb-adjacent region)
  // NOTE: xn stored in kf/vf region? No — use dedicated: reuse xc (dead after conv).
  ln_split<<<dim3(1024, 2), blk, 0, stream>>>(xr, bsr, gamma, beta, xc);

  // q projection -> fp16 q row-major (pre-scaled by hd^-0.5 * log2e), into qb2 (xr dead)
  gemm_sp<<<dim3(8, 64, 2), blk, 0, stream>>>(xq, xq + 2097152, WqTp,
      4096, 512, 16, 16, 1, 2, nullptr, qb2, 0.125f * 1.4426950408889634f);

  // kv projection -> fp16 kv row-major (A = xn frag-packed in xc, branch stride 524288)
  gemm_sp<<<dim3(16, 16, 2), blk, 0, stream>>>(xc, xc + 524288, WkvTp,
      1024, 1024, 16, 16, 1, 2, nullptr, kvb, 1.0f);

  // pack K and V^T into MFMA fragment layout
  kvpack<<<1024, blk, 0, stream>>>(kvb, kf, vf);

  // attention -> ao frag-packed fp16 (into xq region)
  attn_mfma<<<dim3(128, 8, 2), blk, 0, stream>>>(qb2, kf, vf, aop);

  // fused output projection + bias + mask + token exchange -> final out
  gemm_out<<<dim3(8, 64), blk, 0, stream>>>(aop, WpTp, bp, mask0, mask1, out);
}